// Round 1
// baseline (497.346 us; speedup 1.0000x reference)
//
#include <hip/hip_runtime.h>

#define B_ROWS 4096
#define K_Q    32768
#define D_DIM  256
#define C_CLS  100

typedef unsigned short u16;
typedef __attribute__((ext_vector_type(8))) short short8_t;   // 8 bf16 (4 VGPR)
typedef __attribute__((ext_vector_type(4))) float f32x4;

#define GLDS16(g, l) __builtin_amdgcn_global_load_lds( \
    (const __attribute__((address_space(1))) unsigned int*)(g), \
    (__attribute__((address_space(3))) unsigned int*)(l), 16, 0, 0)

__device__ inline u16 f2bf(float x) {   // RNE float->bf16
  unsigned int u = __float_as_uint(x);
  u = (u + 0x7FFFu + ((u >> 16) & 1u)) >> 16;
  return (u16)u;
}

// ---------- K1: per-class sums + counts (LDS histogram, split K x D) ----------
__global__ void k_hist(const float* __restrict__ q, const int* __restrict__ lab,
                       int* __restrict__ counts, float* __restrict__ sums) {
  const int kc = blockIdx.x;   // 32 K-chunks of 1024
  const int dc = blockIdx.y;   // 4 D-chunks of 64
  __shared__ float lsum[C_CLS * 64];
  __shared__ int lcnt[C_CLS];
  const int tid = threadIdx.x;
  for (int i = tid; i < C_CLS * 64; i += 256) lsum[i] = 0.f;
  if (dc == 0 && tid < C_CLS) lcnt[tid] = 0;
  __syncthreads();
  const int kk = tid >> 6, dd = tid & 63;      // wave id, lane
  const int k0 = kc * 1024;
  for (int k = k0 + kk; k < k0 + 1024; k += 4) {
    int c = lab[k];                             // wave-uniform broadcast
    float v = q[(size_t)k * D_DIM + dc * 64 + dd];
    atomicAdd(&lsum[c * 64 + dd], v);           // 64 consecutive floats: conflict-free
    if (dc == 0 && dd == 0) atomicAdd(&lcnt[c], 1);
  }
  __syncthreads();
  for (int i = tid; i < C_CLS * 64; i += 256) {
    int c = i >> 6, d = i & 63;
    atomicAdd(&sums[c * D_DIM + dc * 64 + d], lsum[i]);
  }
  if (dc == 0 && tid < C_CLS) atomicAdd(&counts[tid], lcnt[tid]);
}

// ---------- K2: centroid normalize ----------
__global__ void k_cnorm(const int* __restrict__ counts, const float* __restrict__ sums,
                        float* __restrict__ cnorm) {
  __shared__ float red[4];
  const int c = blockIdx.x, d = threadIdx.x;    // 256 threads = D
  float cnt = (float)counts[c];
  float v = sums[c * D_DIM + d] / cnt;
  float ss = v * v;
  #pragma unroll
  for (int o = 1; o < 64; o <<= 1) ss += __shfl_xor(ss, o);
  if ((d & 63) == 0) red[d >> 6] = ss;
  __syncthreads();
  float norm = sqrtf(red[0] + red[1] + red[2] + red[3]);
  cnorm[c * D_DIM + d] = v / fmaxf(norm, 1e-12f);
}

// ---------- K3: pseudo-labels (fp32 argmax; 8 lanes per row) ----------
__global__ void k_pseudo(const float* __restrict__ bf, const float* __restrict__ cn,
                         int* __restrict__ pseudo) {
  const int tid = threadIdx.x;
  const int rloc = tid >> 3;                    // 32 rows/block
  const int sub = tid & 7;                      // 8 lanes/row
  const int row = blockIdx.x * 32 + rloc;
  float4 a[8];
  const float4* ap = (const float4*)(bf + (size_t)row * D_DIM);
  #pragma unroll
  for (int j = 0; j < 8; ++j) a[j] = ap[sub + j * 8];
  float best = -1e30f; int bi = 0;
  for (int c = 0; c < C_CLS; ++c) {
    const float4* cp = (const float4*)(cn + c * D_DIM);
    float s = 0.f;
    #pragma unroll
    for (int j = 0; j < 8; ++j) {
      float4 b = cp[sub + j * 8];
      s += a[j].x * b.x + a[j].y * b.y + a[j].z * b.z + a[j].w * b.w;
    }
    s += __shfl_xor(s, 1); s += __shfl_xor(s, 2); s += __shfl_xor(s, 4);
    if (s > best) { best = s; bi = c; }         // strict > keeps first index (jnp.argmax)
  }
  if (sub == 0) pseudo[row] = bi;
}

// ---------- K4: fp32 -> bf16 cast (vectorized) ----------
__global__ void k_cast(const float* __restrict__ in, u16* __restrict__ out, int n4) {
  int i = blockIdx.x * 256 + threadIdx.x;
  if (i >= n4) return;
  float4 v = ((const float4*)in)[i];
  ushort4 o;
  o.x = f2bf(v.x); o.y = f2bf(v.y); o.z = f2bf(v.z); o.w = f2bf(v.w);
  ((ushort4*)out)[i] = o;
}

// ---------- K5: fused bf16 MFMA GEMM + sqrt + masked row-sums ----------
// 128x128 tile, BK=32, 4 waves (2x2 of 64x64), m97-style staging.
__global__ __launch_bounds__(256) void k_main(
    const u16* __restrict__ Abf, const u16* __restrict__ Qbf,
    const int* __restrict__ lab, const int* __restrict__ pseudo,
    float* __restrict__ S_all, float* __restrict__ S_match) {
  __shared__ u16 As[2][128 * 32];     // 8KB each buf
  __shared__ u16 Qs[2][128 * 32];
  __shared__ int lab_s[128];
  __shared__ int ps_s[128];

  const int cb = blockIdx.x;          // 256 col-blocks (queue)
  const int rb = blockIdx.y;          // 32 row-blocks (batch)
  const int tid = threadIdx.x;
  const int w = tid >> 6, l = tid & 63;

  if (tid < 128) lab_s[tid] = lab[cb * 128 + tid];
  else           ps_s[tid - 128] = pseudo[rb * 128 + (tid - 128)];

  // staging: wave-linear LDS dest (lane*16B), per-lane global src
  const int srow = w * 16 + (l >> 2);           // 0..63
  const int sde  = (l & 3) * 8;                 // element offset in row
  const u16* gA = Abf + (size_t)(rb * 128 + srow) * D_DIM + sde;
  const u16* gQ = Qbf + (size_t)(cb * 128 + srow) * D_DIM + sde;
  u16* lA = &As[0][srow * 32 + sde];            // = base + w*1024B + l*16B
  u16* lQ = &Qs[0][srow * 32 + sde];

  f32x4 acc[4][4];
  #pragma unroll
  for (int m = 0; m < 4; ++m)
    #pragma unroll
    for (int n = 0; n < 4; ++n)
      #pragma unroll
      for (int j = 0; j < 4; ++j) acc[m][n][j] = 0.f;

  const int wr = w >> 1, wc = w & 1;
  const int mrow = wr * 64, ncol = wc * 64;
  const int q16 = l & 15, hi = l >> 4;
  const int aoff = (mrow + q16) * 32 + hi * 8;  // A-frag: row = l&15, k = (l>>4)*8..+8
  const int boff = (ncol + q16) * 32 + hi * 8;

  // prologue: stage kt=0 into buf 0
  GLDS16(gA, lA);
  GLDS16(gA + 64 * D_DIM, lA + 64 * 32);
  GLDS16(gQ, lQ);
  GLDS16(gQ + 64 * D_DIM, lQ + 64 * 32);

  #pragma unroll
  for (int kt = 0; kt < 8; ++kt) {
    __syncthreads();                            // drains vmcnt: buf[kt&1] ready
    if (kt + 1 < 8) {                           // prefetch next, overlaps compute
      const int nb = (kt + 1) & 1;
      const u16* a0 = gA + (kt + 1) * 32;
      const u16* q0 = gQ + (kt + 1) * 32;
      GLDS16(a0, lA + nb * 4096);
      GLDS16(a0 + 64 * D_DIM, lA + nb * 4096 + 64 * 32);
      GLDS16(q0, lQ + nb * 4096);
      GLDS16(q0 + 64 * D_DIM, lQ + nb * 4096 + 64 * 32);
    }
    const u16* as = As[kt & 1];
    const u16* qs = Qs[kt & 1];
    short8_t a[4], b[4];
    #pragma unroll
    for (int m = 0; m < 4; ++m) a[m] = *(const short8_t*)(as + aoff + m * 16 * 32);
    #pragma unroll
    for (int n = 0; n < 4; ++n) b[n] = *(const short8_t*)(qs + boff + n * 16 * 32);
    #pragma unroll
    for (int m = 0; m < 4; ++m)
      #pragma unroll
      for (int n = 0; n < 4; ++n)
        acc[m][n] = __builtin_amdgcn_mfma_f32_16x16x32_bf16(a[m], b[n], acc[m][n], 0, 0, 0);
  }

  // epilogue: MAE + masked row sums. C/D layout: col=lane&15, row=(lane>>4)*4+reg
  #pragma unroll
  for (int m = 0; m < 4; ++m) {
    #pragma unroll
    for (int j = 0; j < 4; ++j) {
      const int rl = mrow + m * 16 + hi * 4 + j;
      const int p = ps_s[rl];
      float aAll = 0.f, aM = 0.f;
      #pragma unroll
      for (int n = 0; n < 4; ++n) {
        float s = acc[m][n][j];
        float mae = sqrtf(fmaxf(2.0f - 2.0f * s + 1.0e-6f, 0.0f));
        aAll += mae;
        if (lab_s[ncol + n * 16 + q16] == p) aM += mae;
      }
      aAll += __shfl_xor(aAll, 1); aAll += __shfl_xor(aAll, 2);
      aAll += __shfl_xor(aAll, 4); aAll += __shfl_xor(aAll, 8);
      aM += __shfl_xor(aM, 1); aM += __shfl_xor(aM, 2);
      aM += __shfl_xor(aM, 4); aM += __shfl_xor(aM, 8);
      if (q16 == 0) {
        const int gr = rb * 128 + rl;
        atomicAdd(&S_all[gr], aAll);
        atomicAdd(&S_match[gr], aM);
      }
    }
  }
}

// ---------- K6: final scalar ----------
__global__ void k_final(const float* __restrict__ S_all, const float* __restrict__ S_match,
                        const int* __restrict__ pseudo, const int* __restrict__ counts,
                        float* __restrict__ out) {
  __shared__ float r1[4], r2[4];
  const int tid = threadIdx.x;
  float s1 = 0.f, s2 = 0.f;
  for (int b = tid; b < B_ROWS; b += 256) {
    float cnt = (float)counts[pseudo[b]];       // = sum(maskf) exactly
    float sm = S_match[b], sa = S_all[b];
    s1 += sm / (cnt + 1e-6f);
    s2 += (sa - sm) / ((float)K_Q - cnt + 1e-6f);
  }
  #pragma unroll
  for (int o = 1; o < 64; o <<= 1) { s1 += __shfl_xor(s1, o); s2 += __shfl_xor(s2, o); }
  if ((tid & 63) == 0) { r1[tid >> 6] = s1; r2[tid >> 6] = s2; }
  __syncthreads();
  if (tid == 0) {
    float t1 = r1[0] + r1[1] + r1[2] + r1[3];
    float t2 = r2[0] + r2[1] + r2[2] + r2[3];
    out[0] = t1 / (float)B_ROWS + 2.0f - t2 / (float)B_ROWS;
  }
}

extern "C" void kernel_launch(void* const* d_in, const int* in_sizes, int n_in,
                              void* d_out, int out_size, void* d_ws, size_t ws_size,
                              hipStream_t stream) {
  const float* batch = (const float*)d_in[0];
  const float* queue = (const float*)d_in[1];
  const int*   lab   = (const int*)d_in[2];
  // d_in[3] = num_classes (100), hardcoded

  char* ws = (char*)d_ws;
  // layout: [counts 512B][sums 100KB][S_all 16KB][S_match 16KB] <- zeroed prefix
  //         [cnorm 100KB][pseudo 16KB][Abf 2MB][Qbf 16MB]   total ~18.3MB
  int*   counts  = (int*)  (ws + 0);
  float* sums    = (float*)(ws + 512);
  float* S_all   = (float*)(ws + 102912);
  float* S_match = (float*)(ws + 119296);
  float* cnorm   = (float*)(ws + 135680);
  int*   pseudo  = (int*)  (ws + 238080);
  u16*   Abf     = (u16*)  (ws + 254464);
  u16*   Qbf     = (u16*)  (ws + 254464 + 2097152);

  hipMemsetAsync(d_ws, 0, 135680, stream);      // counts+sums+S_all+S_match

  k_hist  <<<dim3(32, 4), 256, 0, stream>>>(queue, lab, counts, sums);
  k_cnorm <<<C_CLS, 256, 0, stream>>>(counts, sums, cnorm);
  k_pseudo<<<B_ROWS / 32, 256, 0, stream>>>(batch, cnorm, pseudo);
  k_cast  <<<(B_ROWS * D_DIM / 4 + 255) / 256, 256, 0, stream>>>(batch, Abf, B_ROWS * D_DIM / 4);
  k_cast  <<<(K_Q * D_DIM / 4 + 255) / 256, 256, 0, stream>>>(queue, Qbf, K_Q * D_DIM / 4);
  k_main  <<<dim3(K_Q / 128, B_ROWS / 128), 256, 0, stream>>>(Abf, Qbf, lab, pseudo, S_all, S_match);
  k_final <<<1, 256, 0, stream>>>(S_all, S_match, pseudo, counts, (float*)d_out);
}

// Round 2
// 320.803 us; speedup vs baseline: 1.5503x; 1.5503x over previous
//
#include <hip/hip_runtime.h>

#define B_ROWS 4096
#define K_Q    32768
#define D_DIM  256
#define C_CLS  100

typedef unsigned short u16;
typedef __attribute__((ext_vector_type(8))) short short8_t;   // 8 bf16 (4 VGPR)
typedef __attribute__((ext_vector_type(4))) float f32x4;

__device__ inline u16 f2bf(float x) {   // RNE float->bf16
  unsigned int u = __float_as_uint(x);
  u = (u + 0x7FFFu + ((u >> 16) & 1u)) >> 16;
  return (u16)u;
}

// ---------- K1: per-class sums + counts (LDS histogram, split K x D) ----------
__global__ void k_hist(const float* __restrict__ q, const int* __restrict__ lab,
                       int* __restrict__ counts, float* __restrict__ sums) {
  const int kc = blockIdx.x;   // 32 K-chunks of 1024
  const int dc = blockIdx.y;   // 4 D-chunks of 64
  __shared__ float lsum[C_CLS * 64];
  __shared__ int lcnt[C_CLS];
  const int tid = threadIdx.x;
  for (int i = tid; i < C_CLS * 64; i += 256) lsum[i] = 0.f;
  if (dc == 0 && tid < C_CLS) lcnt[tid] = 0;
  __syncthreads();
  const int kk = tid >> 6, dd = tid & 63;
  const int k0 = kc * 1024;
  for (int k = k0 + kk; k < k0 + 1024; k += 4) {
    int c = lab[k];
    float v = q[(size_t)k * D_DIM + dc * 64 + dd];
    atomicAdd(&lsum[c * 64 + dd], v);
    if (dc == 0 && dd == 0) atomicAdd(&lcnt[c], 1);
  }
  __syncthreads();
  for (int i = tid; i < C_CLS * 64; i += 256) {
    int c = i >> 6, d = i & 63;
    atomicAdd(&sums[c * D_DIM + dc * 64 + d], lsum[i]);
  }
  if (dc == 0 && tid < C_CLS) atomicAdd(&counts[tid], lcnt[tid]);
}

// ---------- K2: centroid normalize ----------
__global__ void k_cnorm(const int* __restrict__ counts, const float* __restrict__ sums,
                        float* __restrict__ cnorm) {
  __shared__ float red[4];
  const int c = blockIdx.x, d = threadIdx.x;
  float cnt = (float)counts[c];
  float v = sums[c * D_DIM + d] / cnt;
  float ss = v * v;
  #pragma unroll
  for (int o = 1; o < 64; o <<= 1) ss += __shfl_xor(ss, o);
  if ((d & 63) == 0) red[d >> 6] = ss;
  __syncthreads();
  float norm = sqrtf(red[0] + red[1] + red[2] + red[3]);
  cnorm[c * D_DIM + d] = v / fmaxf(norm, 1e-12f);
}

// ---------- K3: pseudo-labels (fp32 argmax; 8 lanes per row) ----------
__global__ void k_pseudo(const float* __restrict__ bf, const float* __restrict__ cn,
                         int* __restrict__ pseudo) {
  const int tid = threadIdx.x;
  const int rloc = tid >> 3;
  const int sub = tid & 7;
  const int row = blockIdx.x * 32 + rloc;
  float4 a[8];
  const float4* ap = (const float4*)(bf + (size_t)row * D_DIM);
  #pragma unroll
  for (int j = 0; j < 8; ++j) a[j] = ap[sub + j * 8];
  float best = -1e30f; int bi = 0;
  for (int c = 0; c < C_CLS; ++c) {
    const float4* cp = (const float4*)(cn + c * D_DIM);
    float s = 0.f;
    #pragma unroll
    for (int j = 0; j < 8; ++j) {
      float4 b = cp[sub + j * 8];
      s += a[j].x * b.x + a[j].y * b.y + a[j].z * b.z + a[j].w * b.w;
    }
    s += __shfl_xor(s, 1); s += __shfl_xor(s, 2); s += __shfl_xor(s, 4);
    if (s > best) { best = s; bi = c; }
  }
  if (sub == 0) pseudo[row] = bi;
}

// ---------- K4: fp32 -> bf16 cast (vectorized) ----------
__global__ void k_cast(const float* __restrict__ in, u16* __restrict__ out, int n4) {
  int i = blockIdx.x * 256 + threadIdx.x;
  if (i >= n4) return;
  float4 v = ((const float4*)in)[i];
  ushort4 o;
  o.x = f2bf(v.x); o.y = f2bf(v.y); o.z = f2bf(v.z); o.w = f2bf(v.w);
  ((ushort4*)out)[i] = o;
}

// ---------- K5: fused bf16 MFMA GEMM + sqrt + masked row-sums ----------
// Block: 128 batch rows x 2048 queue cols (16 tiles of 128).
// 512 threads = 8 waves (4 row-groups x 2 col-halves); per wave 32x64, m-rep 2, n-rep 4.
// A-fragments in registers (loaded once); Q reg-staged into transposed+XOR LDS (conflict-free);
// row-sum partials in registers, one shfl-reduce + atomic pass per block.
__global__ __launch_bounds__(512) void k_main(
    const u16* __restrict__ Abf, const u16* __restrict__ Qbf,
    const int* __restrict__ lab, const int* __restrict__ pseudo,
    float* __restrict__ S_all, float* __restrict__ S_match) {
  __shared__ u16 Qs[2][4096];         // 2 x 8KB: [k4:4][slot = row^k4 :128] granules of 8 bf16

  // XCD-bijective swizzle, cs-major chunks: 64 consecutive blocks per XCD share
  // 2 Q-slices (2MB) + all of A (2MB) = one 4MB L2.
  const int bid = blockIdx.x;
  const int o = (bid & 7) * 64 + (bid >> 3);
  const int cs = o >> 5;              // 0..15 column slice (2048 cols)
  const int rb = o & 31;              // 0..31 row block (128 rows)

  const int tid = threadIdx.x;
  const int w = tid >> 6;
  const int wr = w >> 1, wc = w & 1;
  const int q16 = tid & 15, hi = (tid & 63) >> 4;
  const int rowA = rb * 128 + wr * 32;
  const int ncol_w = wc * 64;

  // ---- A-fragments: 2 (m) x 8 (kt) short8 = 64 VGPR, loaded once ----
  short8_t areg[2][8];
  #pragma unroll
  for (int m = 0; m < 2; ++m)
    #pragma unroll
    for (int kt = 0; kt < 8; ++kt)
      areg[m][kt] = *(const short8_t*)(Abf + (size_t)(rowA + m * 16 + q16) * D_DIM + kt * 32 + hi * 8);

  // ---- pseudo-labels for this lane's 8 rows ----
  int pse[2][4];
  #pragma unroll
  for (int m = 0; m < 2; ++m)
    #pragma unroll
    for (int j = 0; j < 4; ++j)
      pse[m][j] = pseudo[rowA + m * 16 + hi * 4 + j];

  float pa[2][4], pm_[2][4];
  #pragma unroll
  for (int m = 0; m < 2; ++m)
    #pragma unroll
    for (int j = 0; j < 4; ++j) { pa[m][j] = 0.f; pm_[m][j] = 0.f; }

  // staging map: thread -> granule (row r = tid>>2, k4 = tid&3); quad = 64B coalesced
  const int sr = tid >> 2, sk4 = tid & 3;
  const int swoff = sk4 * 1024 + ((sr ^ sk4) * 8);          // LDS elem offset (swizzled)
  const int colbase = cs * 2048;

  // prologue: stage (cb=0, kt=0) into buf 0
  short8_t qreg = *(const short8_t*)(Qbf + (size_t)(colbase + sr) * D_DIM + sk4 * 8);
  *(short8_t*)(&Qs[0][swoff]) = qreg;

  #pragma unroll 1
  for (int cb = 0; cb < 16; ++cb) {
    // labels for this tile (used only in the mae-pass 8 kts later)
    int lbl[4];
    #pragma unroll
    for (int n = 0; n < 4; ++n)
      lbl[n] = lab[colbase + cb * 128 + ncol_w + n * 16 + q16];

    f32x4 acc[2][4];
    #pragma unroll
    for (int m = 0; m < 2; ++m)
      #pragma unroll
      for (int n = 0; n < 4; ++n)
        #pragma unroll
        for (int j = 0; j < 4; ++j) acc[m][n][j] = 0.f;

    #pragma unroll
    for (int kt = 0; kt < 8; ++kt) {
      const int s = cb * 8 + kt;
      __syncthreads();                          // buf[kt&1] ready; buf[(kt+1)&1] free
      if (s + 1 < 128) {                        // issue next-step global load early (T14)
        const int cbn = (s + 1) >> 3, ktn = (s + 1) & 7;
        qreg = *(const short8_t*)(Qbf + (size_t)(colbase + cbn * 128 + sr) * D_DIM + ktn * 32 + sk4 * 8);
      }
      const u16* qs = Qs[kt & 1];
      short8_t b[4];
      #pragma unroll
      for (int n = 0; n < 4; ++n)
        b[n] = *(const short8_t*)(qs + hi * 1024 + (((ncol_w + n * 16 + q16) ^ hi) * 8));
      #pragma unroll
      for (int m = 0; m < 2; ++m)
        #pragma unroll
        for (int n = 0; n < 4; ++n)
          acc[m][n] = __builtin_amdgcn_mfma_f32_16x16x32_bf16(areg[m][kt], b[n], acc[m][n], 0, 0, 0);
      if (s + 1 < 128)                          // write-late into the other buffer
        *(short8_t*)(&Qs[(kt + 1) & 1][swoff]) = qreg;
    }

    // mae-pass: registers only, overlaps other waves' MFMA
    #pragma unroll
    for (int m = 0; m < 2; ++m)
      #pragma unroll
      for (int j = 0; j < 4; ++j) {
        const int p = pse[m][j];
        #pragma unroll
        for (int n = 0; n < 4; ++n) {
          float sv = acc[m][n][j];
          float mae = sqrtf(fmaxf(2.0f - 2.0f * sv + 1.0e-6f, 0.0f));
          pa[m][j] += mae;
          if (lbl[n] == p) pm_[m][j] += mae;
        }
      }
  }

  // ---- once per block: reduce over the 16 q-lanes, 2 atomics per row per wave ----
  #pragma unroll
  for (int m = 0; m < 2; ++m)
    #pragma unroll
    for (int j = 0; j < 4; ++j) {
      float va = pa[m][j], vm = pm_[m][j];
      va += __shfl_xor(va, 1); va += __shfl_xor(va, 2);
      va += __shfl_xor(va, 4); va += __shfl_xor(va, 8);
      vm += __shfl_xor(vm, 1); vm += __shfl_xor(vm, 2);
      vm += __shfl_xor(vm, 4); vm += __shfl_xor(vm, 8);
      if (q16 == 0) {
        const int gr = rowA + m * 16 + hi * 4 + j;
        atomicAdd(&S_all[gr], va);
        atomicAdd(&S_match[gr], vm);
      }
    }
}

// ---------- K6: final scalar ----------
__global__ void k_final(const float* __restrict__ S_all, const float* __restrict__ S_match,
                        const int* __restrict__ pseudo, const int* __restrict__ counts,
                        float* __restrict__ out) {
  __shared__ float r1[4], r2[4];
  const int tid = threadIdx.x;
  float s1 = 0.f, s2 = 0.f;
  for (int b = tid; b < B_ROWS; b += 256) {
    float cnt = (float)counts[pseudo[b]];
    float sm = S_match[b], sa = S_all[b];
    s1 += sm / (cnt + 1e-6f);
    s2 += (sa - sm) / ((float)K_Q - cnt + 1e-6f);
  }
  #pragma unroll
  for (int o = 1; o < 64; o <<= 1) { s1 += __shfl_xor(s1, o); s2 += __shfl_xor(s2, o); }
  if ((tid & 63) == 0) { r1[tid >> 6] = s1; r2[tid >> 6] = s2; }
  __syncthreads();
  if (tid == 0) {
    float t1 = r1[0] + r1[1] + r1[2] + r1[3];
    float t2 = r2[0] + r2[1] + r2[2] + r2[3];
    out[0] = t1 / (float)B_ROWS + 2.0f - t2 / (float)B_ROWS;
  }
}

extern "C" void kernel_launch(void* const* d_in, const int* in_sizes, int n_in,
                              void* d_out, int out_size, void* d_ws, size_t ws_size,
                              hipStream_t stream) {
  const float* batch = (const float*)d_in[0];
  const float* queue = (const float*)d_in[1];
  const int*   lab   = (const int*)d_in[2];

  char* ws = (char*)d_ws;
  int*   counts  = (int*)  (ws + 0);
  float* sums    = (float*)(ws + 512);
  float* S_all   = (float*)(ws + 102912);
  float* S_match = (float*)(ws + 119296);
  float* cnorm   = (float*)(ws + 135680);
  int*   pseudo  = (int*)  (ws + 238080);
  u16*   Abf     = (u16*)  (ws + 254464);
  u16*   Qbf     = (u16*)  (ws + 254464 + 2097152);

  hipMemsetAsync(d_ws, 0, 135680, stream);      // counts+sums+S_all+S_match

  k_hist  <<<dim3(32, 4), 256, 0, stream>>>(queue, lab, counts, sums);
  k_cnorm <<<C_CLS, 256, 0, stream>>>(counts, sums, cnorm);
  k_pseudo<<<B_ROWS / 32, 256, 0, stream>>>(batch, cnorm, pseudo);
  k_cast  <<<(B_ROWS * D_DIM / 4 + 255) / 256, 256, 0, stream>>>(batch, Abf, B_ROWS * D_DIM / 4);
  k_cast  <<<(K_Q * D_DIM / 4 + 255) / 256, 256, 0, stream>>>(queue, Qbf, K_Q * D_DIM / 4);
  k_main  <<<512, 512, 0, stream>>>(Abf, Qbf, lab, pseudo, S_all, S_match);
  k_final <<<1, 256, 0, stream>>>(S_all, S_match, pseudo, counts, (float*)d_out);
}

// Round 3
// 257.256 us; speedup vs baseline: 1.9333x; 1.2470x over previous
//
#include <hip/hip_runtime.h>

#define B_ROWS 4096
#define K_Q    32768
#define D_DIM  256
#define C_CLS  100

typedef unsigned short u16;
typedef __attribute__((ext_vector_type(8))) short short8_t;   // 8 bf16 (4 VGPR)
typedef __attribute__((ext_vector_type(4))) float f32x4;

__device__ inline u16 f2bf(float x) {   // RNE float->bf16
  unsigned int u = __float_as_uint(x);
  u = (u + 0x7FFFu + ((u >> 16) & 1u)) >> 16;
  return (u16)u;
}

// ---------- K1: fused per-class histogram + fp32->bf16 cast of Q ----------
// grid (64 kc x 4 dc), 256 threads. Reads Q once (float4), writes Qbf, accumulates
// class sums/counts via LDS.
__global__ void k_histcast(const float* __restrict__ q, const int* __restrict__ lab,
                           int* __restrict__ counts, float* __restrict__ sums,
                           u16* __restrict__ qbf) {
  const int kc = blockIdx.x;          // 64 chunks of 512 queue rows
  const int dc = blockIdx.y;          // 4 chunks of 64 cols
  __shared__ float lsum[C_CLS * 64];
  __shared__ int lcnt[C_CLS];
  const int tid = threadIdx.x;
  for (int i = tid; i < C_CLS * 64; i += 256) lsum[i] = 0.f;
  if (dc == 0 && tid < C_CLS) lcnt[tid] = 0;
  __syncthreads();

  const int rloc = tid >> 4;          // 16 rows per iteration
  const int c4 = tid & 15;            // float4 slot within 64 cols
  for (int it = 0; it < 32; ++it) {
    const int k = kc * 512 + it * 16 + rloc;
    const int c = lab[k];
    const size_t off = (size_t)k * D_DIM + dc * 64 + c4 * 4;
    float4 v = *(const float4*)(q + off);
    ushort4 o;
    o.x = f2bf(v.x); o.y = f2bf(v.y); o.z = f2bf(v.z); o.w = f2bf(v.w);
    *(ushort4*)(qbf + off) = o;
    const int base = c * 64 + c4 * 4;
    atomicAdd(&lsum[base + 0], v.x);
    atomicAdd(&lsum[base + 1], v.y);
    atomicAdd(&lsum[base + 2], v.z);
    atomicAdd(&lsum[base + 3], v.w);
    if (dc == 0 && c4 == 0) atomicAdd(&lcnt[c], 1);
  }
  __syncthreads();
  for (int i = tid; i < C_CLS * 64; i += 256) {
    int c = i >> 6, d = i & 63;
    atomicAdd(&sums[c * D_DIM + dc * 64 + d], lsum[i]);
  }
  if (dc == 0 && tid < C_CLS) atomicAdd(&counts[tid], lcnt[tid]);
}

// ---------- K2: centroid normalize ----------
__global__ void k_cnorm(const int* __restrict__ counts, const float* __restrict__ sums,
                        float* __restrict__ cnorm) {
  __shared__ float red[4];
  const int c = blockIdx.x, d = threadIdx.x;
  float cnt = (float)counts[c];
  float v = sums[c * D_DIM + d] / cnt;
  float ss = v * v;
  #pragma unroll
  for (int o = 1; o < 64; o <<= 1) ss += __shfl_xor(ss, o);
  if ((d & 63) == 0) red[d >> 6] = ss;
  __syncthreads();
  float norm = sqrtf(red[0] + red[1] + red[2] + red[3]);
  cnorm[c * D_DIM + d] = v / fmaxf(norm, 1e-12f);
}

// ---------- K3: pseudo-labels (fp32 argmax) + fused A bf16 cast ----------
__global__ void k_pseudo(const float* __restrict__ bf, const float* __restrict__ cn,
                         int* __restrict__ pseudo, u16* __restrict__ abf) {
  const int tid = threadIdx.x;
  const int rloc = tid >> 3;
  const int sub = tid & 7;
  const int row = blockIdx.x * 32 + rloc;
  float4 a[8];
  const float4* ap = (const float4*)(bf + (size_t)row * D_DIM);
  #pragma unroll
  for (int j = 0; j < 8; ++j) a[j] = ap[sub + j * 8];
  // fused cast-store of this row's elements
  #pragma unroll
  for (int j = 0; j < 8; ++j) {
    ushort4 o;
    o.x = f2bf(a[j].x); o.y = f2bf(a[j].y); o.z = f2bf(a[j].z); o.w = f2bf(a[j].w);
    *(ushort4*)(abf + (size_t)row * D_DIM + (sub + j * 8) * 4) = o;
  }
  float best = -1e30f; int bi = 0;
  for (int c = 0; c < C_CLS; ++c) {
    const float4* cp = (const float4*)(cn + c * D_DIM);
    float s = 0.f;
    #pragma unroll
    for (int j = 0; j < 8; ++j) {
      float4 b = cp[sub + j * 8];
      s += a[j].x * b.x + a[j].y * b.y + a[j].z * b.z + a[j].w * b.w;
    }
    s += __shfl_xor(s, 1); s += __shfl_xor(s, 2); s += __shfl_xor(s, 4);
    if (s > best) { best = s; bi = c; }         // strict > = first index (jnp.argmax)
  }
  if (sub == 0) pseudo[row] = bi;
}

// ---------- K5: fused bf16 MFMA GEMM + sqrt + masked row-sums (no LDS) ----------
// Block: 4 waves (2wr x 2wc). Wave = 64 rows x 32 cols per step; block = 128 rows
// x 2048-col slice, 32 steps of 64 cols. A-fragments resident in registers
// (loaded once); B-fragments loaded per-lane straight from global (L1/L2-resident
// Q slice; B-frag layout == row-major 16B load). No LDS, no staging, no barriers
// except a per-step alignment barrier for L1 reuse across wr-pairs.
__global__ __launch_bounds__(256, 2) void k_main(
    const u16* __restrict__ Abf, const u16* __restrict__ Qbf,
    const int* __restrict__ lab, const int* __restrict__ pseudo,
    float* __restrict__ S_all, float* __restrict__ S_match) {
  // XCD-bijective swizzle (512 % 8 == 0): xcd = bid&7 keeps 2 col-slices (4MB Q)
  // per XCD L2, all 32 row-blocks over them.
  const int bid = blockIdx.x;
  const int o = (bid & 7) * 64 + (bid >> 3);
  const int cs = o >> 5;              // 0..15 col slice (2048 cols)
  const int rb = o & 31;              // 0..31 row block (128 rows)

  const int tid = threadIdx.x;
  const int w = tid >> 6;
  const int wr = w >> 1, wc = w & 1;
  const int l = tid & 63;
  const int q16 = l & 15, hi = l >> 4;
  const int rowA = rb * 128 + wr * 64;          // wave's 64 rows
  const int colW = cs * 2048 + wc * 32;         // wave's col base

  // A-fragments: 4(m) x 8(kt) short8 = 128 VGPR, loaded once
  short8_t areg[4][8];
  #pragma unroll
  for (int m = 0; m < 4; ++m)
    #pragma unroll
    for (int kt = 0; kt < 8; ++kt)
      areg[m][kt] = *(const short8_t*)(Abf + (size_t)(rowA + m * 16 + q16) * D_DIM + kt * 32 + hi * 8);

  int pse[4][4];
  #pragma unroll
  for (int m = 0; m < 4; ++m)
    #pragma unroll
    for (int j = 0; j < 4; ++j)
      pse[m][j] = pseudo[rowA + m * 16 + hi * 4 + j];

  float pa[4][4], pm_[4][4];
  #pragma unroll
  for (int m = 0; m < 4; ++m)
    #pragma unroll
    for (int j = 0; j < 4; ++j) { pa[m][j] = 0.f; pm_[m][j] = 0.f; }

  const u16* bbase = Qbf + (size_t)(colW + q16) * D_DIM + hi * 8;
  const int* lbase = lab + colW + q16;

  #pragma unroll 1
  for (int cb = 0; cb < 32; ++cb) {
    const int lbl0 = lbase[cb * 64];
    const int lbl1 = lbase[cb * 64 + 16];

    f32x4 acc[4][2];
    #pragma unroll
    for (int m = 0; m < 4; ++m)
      #pragma unroll
      for (int n = 0; n < 2; ++n)
        #pragma unroll
        for (int j = 0; j < 4; ++j) acc[m][n][j] = 0.f;

    const u16* bp = bbase + (size_t)(cb * 64) * D_DIM;
    #pragma unroll
    for (int kt = 0; kt < 8; ++kt) {
      short8_t b0 = *(const short8_t*)(bp + kt * 32);
      short8_t b1 = *(const short8_t*)(bp + 16 * D_DIM + kt * 32);
      #pragma unroll
      for (int m = 0; m < 4; ++m)
        acc[m][0] = __builtin_amdgcn_mfma_f32_16x16x32_bf16(areg[m][kt], b0, acc[m][0], 0, 0, 0);
      #pragma unroll
      for (int m = 0; m < 4; ++m)
        acc[m][1] = __builtin_amdgcn_mfma_f32_16x16x32_bf16(areg[m][kt], b1, acc[m][1], 0, 0, 0);
    }

    // MAE epilogue for this 64-col step (registers only)
    #pragma unroll
    for (int m = 0; m < 4; ++m)
      #pragma unroll
      for (int j = 0; j < 4; ++j) {
        const int p = pse[m][j];
        float s0 = acc[m][0][j];
        float mae0 = sqrtf(fmaxf(2.0f - 2.0f * s0 + 1.0e-6f, 0.0f));
        pa[m][j] += mae0;
        if (lbl0 == p) pm_[m][j] += mae0;
        float s1 = acc[m][1][j];
        float mae1 = sqrtf(fmaxf(2.0f - 2.0f * s1 + 1.0e-6f, 0.0f));
        pa[m][j] += mae1;
        if (lbl1 == p) pm_[m][j] += mae1;
      }
    __syncthreads();   // alignment only: keep wr-pairs on the same B-tile for L1 reuse
  }

  // once per block: reduce over 16 q-lanes, then atomics
  #pragma unroll
  for (int m = 0; m < 4; ++m)
    #pragma unroll
    for (int j = 0; j < 4; ++j) {
      float va = pa[m][j], vm = pm_[m][j];
      va += __shfl_xor(va, 1); va += __shfl_xor(va, 2);
      va += __shfl_xor(va, 4); va += __shfl_xor(va, 8);
      vm += __shfl_xor(vm, 1); vm += __shfl_xor(vm, 2);
      vm += __shfl_xor(vm, 4); vm += __shfl_xor(vm, 8);
      if (q16 == 0) {
        const int gr = rowA + m * 16 + hi * 4 + j;
        atomicAdd(&S_all[gr], va);
        atomicAdd(&S_match[gr], vm);
      }
    }
}

// ---------- K6: final scalar ----------
__global__ void k_final(const float* __restrict__ S_all, const float* __restrict__ S_match,
                        const int* __restrict__ pseudo, const int* __restrict__ counts,
                        float* __restrict__ out) {
  __shared__ float r1[4], r2[4];
  const int tid = threadIdx.x;
  float s1 = 0.f, s2 = 0.f;
  for (int b = tid; b < B_ROWS; b += 256) {
    float cnt = (float)counts[pseudo[b]];
    float sm = S_match[b], sa = S_all[b];
    s1 += sm / (cnt + 1e-6f);
    s2 += (sa - sm) / ((float)K_Q - cnt + 1e-6f);
  }
  #pragma unroll
  for (int o = 1; o < 64; o <<= 1) { s1 += __shfl_xor(s1, o); s2 += __shfl_xor(s2, o); }
  if ((tid & 63) == 0) { r1[tid >> 6] = s1; r2[tid >> 6] = s2; }
  __syncthreads();
  if (tid == 0) {
    float t1 = r1[0] + r1[1] + r1[2] + r1[3];
    float t2 = r2[0] + r2[1] + r2[2] + r2[3];
    out[0] = t1 / (float)B_ROWS + 2.0f - t2 / (float)B_ROWS;
  }
}

extern "C" void kernel_launch(void* const* d_in, const int* in_sizes, int n_in,
                              void* d_out, int out_size, void* d_ws, size_t ws_size,
                              hipStream_t stream) {
  const float* batch = (const float*)d_in[0];
  const float* queue = (const float*)d_in[1];
  const int*   lab   = (const int*)d_in[2];

  char* ws = (char*)d_ws;
  int*   counts  = (int*)  (ws + 0);
  float* sums    = (float*)(ws + 512);
  float* S_all   = (float*)(ws + 102912);
  float* S_match = (float*)(ws + 119296);
  float* cnorm   = (float*)(ws + 135680);
  int*   pseudo  = (int*)  (ws + 238080);
  u16*   Abf     = (u16*)  (ws + 254464);
  u16*   Qbf     = (u16*)  (ws + 254464 + 2097152);

  hipMemsetAsync(d_ws, 0, 135680, stream);      // counts+sums+S_all+S_match

  k_histcast<<<dim3(64, 4), 256, 0, stream>>>(queue, lab, counts, sums, Qbf);
  k_cnorm   <<<C_CLS, 256, 0, stream>>>(counts, sums, cnorm);
  k_pseudo  <<<B_ROWS / 32, 256, 0, stream>>>(batch, cnorm, pseudo, Abf);
  k_main    <<<512, 256, 0, stream>>>(Abf, Qbf, lab, pseudo, S_all, S_match);
  k_final   <<<1, 256, 0, stream>>>(S_all, S_match, pseudo, counts, (float*)d_out);
}